// Round 1
// baseline (488.982 us; speedup 1.0000x reference)
//
#include <hip/hip_runtime.h>

// RNN: B=4096, T=512, I=15, H=64, O=1
// out[b] = fc( scan_t h = tanh(x_t W_ih^T + b_ih + b_hh + h W_hh^T) )
//
// Design: 256 blocks x 256 threads; block owns 16 batch rows for all 512 steps.
// Augmented GEMM per step: preact[16b][64j] = A[16][96] * Waug[96][64]
//   A = [h (64) | x_t (15) | pad (17)] in bf16 hi+lo (double-buffered LDS)
//   Waug = [W_hh^T ; W_ih^T ; 0]     in bf16 hi+lo (registers, loaded once)
// bf16x3: hi*hi + lo*hi + hi*lo -> ~fp32 accuracy (needed: 512-step recurrence).
// Wave w handles j in [16w,16w+16): 3 K-chunks x 3 terms = 9 MFMA/wave/step.

#define T_STEPS 512
#define I_DIM 15
#define BPB 16            // batches per block
#define ROWSH 104         // LDS row stride in shorts (64+15+pad; 20m%32 -> 2-way banks)

typedef __attribute__((ext_vector_type(8))) short short8;
typedef __attribute__((ext_vector_type(4))) float float4v;

__device__ __forceinline__ short f2bf(float f) {
    union { float f; unsigned u; } v; v.f = f;
    unsigned r = (v.u + 0x7FFFu + ((v.u >> 16) & 1u)) >> 16;   // RNE
    return (short)r;
}
__device__ __forceinline__ float bf2f(short s) {
    union { float f; unsigned u; } v;
    v.u = ((unsigned)(unsigned short)s) << 16;
    return v.f;
}
__device__ __forceinline__ float fast_tanh(float x) {
    x = fminf(30.f, fmaxf(-30.f, x));
    float e = __builtin_exp2f(x * 2.8853900817779268f);  // e^(2x)
    return (e - 1.f) * __builtin_amdgcn_rcpf(e + 1.f);
}

__global__ __launch_bounds__(256) void rnn_fused(
    const float* __restrict__ x,     // [4096][512][15]
    const float* __restrict__ W_ih,  // [64][15]
    const float* __restrict__ W_hh,  // [64][64]
    const float* __restrict__ b_ih,  // [64]
    const float* __restrict__ b_hh,  // [64]
    const float* __restrict__ fc_w,  // [1][64]
    const float* __restrict__ fc_b,  // [1]
    float* __restrict__ out)         // [4096]
{
    __shared__ __align__(16) short Ahi[2][BPB][ROWSH];
    __shared__ __align__(16) short Alo[2][BPB][ROWSH];
    __shared__ float hfin[BPB][65];

    const int tid  = threadIdx.x;
    const int wave = tid >> 6;
    const int lane = tid & 63;
    const int q    = lane >> 4;     // quad
    const int n    = lane & 15;     // A-row (batch) on read; C/D col (j) on write
    const int j    = wave * 16 + n; // hidden column this lane accumulates
    const int b0   = blockIdx.x * BPB;

    // zero LDS (h0 = 0 and pad columns must be 0 in both buffers)
    for (int idx = tid; idx < 2 * BPB * ROWSH; idx += 256) {
        ((short*)Ahi)[idx] = 0;
        ((short*)Alo)[idx] = 0;
    }

    // --- B fragments (Waug columns for this lane's j), hi+lo, kept in regs ---
    // B layout mirrors A: value Waug[k][n'] with n'=lane&15 -> j, k = c*32 + q*8 + e
    short8 bhi[3], blo[3];
    for (int c = 0; c < 3; c++) {
        for (int e = 0; e < 8; e++) {
            int k = c * 32 + q * 8 + e;
            float w = 0.f;
            if (k < 64)       w = W_hh[j * 64 + k];
            else if (k < 79)  w = W_ih[j * 15 + (k - 64)];
            short hi = f2bf(w);
            float rem = w - bf2f(hi);
            bhi[c][e] = hi;
            blo[c][e] = f2bf(rem);
        }
    }
    const float bias = b_ih[j] + b_hh[j];  // fp32, folded in after MFMA

    // x staging role: thread tid<240 loads x[b0+xb][t][xi]
    const int xb = tid / I_DIM, xi = tid - xb * I_DIM;
    const bool xactive = tid < BPB * I_DIM;
    const size_t xbase = (size_t)(b0 + xb) * T_STEPS * I_DIM + xi;

    if (xactive) {  // stage x(0) into buf 0
        float v = x[xbase];
        short hi = f2bf(v);
        Ahi[0][xb][64 + xi] = hi;
        Alo[0][xb][64 + xi] = f2bf(v - bf2f(hi));
    }
    __syncthreads();

    float hreg[4] = {0.f, 0.f, 0.f, 0.f};

    for (int t = 0; t < T_STEPS; t++) {
        const int p = t & 1, pn = p ^ 1;

        // A fragments: row m = n (batch), k = c*32 + q*8 + e  (ds_read_b128)
        const short* rowh = &Ahi[p][n][0];
        const short* rowl = &Alo[p][n][0];
        short8 ahi0 = *(const short8*)(rowh + 0 * 32 + q * 8);
        short8 alo0 = *(const short8*)(rowl + 0 * 32 + q * 8);
        short8 ahi1 = *(const short8*)(rowh + 1 * 32 + q * 8);
        short8 alo1 = *(const short8*)(rowl + 1 * 32 + q * 8);
        short8 ahi2 = *(const short8*)(rowh + 2 * 32 + q * 8);
        short8 alo2 = *(const short8*)(rowl + 2 * 32 + q * 8);

        // stage x(t+1) into the other buffer (no dependency on this step's math)
        if (t + 1 < T_STEPS && xactive) {
            float v = x[xbase + (size_t)(t + 1) * I_DIM];
            short hi = f2bf(v);
            Ahi[pn][xb][64 + xi] = hi;
            Alo[pn][xb][64 + xi] = f2bf(v - bf2f(hi));
        }

        float4v acc = {0.f, 0.f, 0.f, 0.f};
        acc = __builtin_amdgcn_mfma_f32_16x16x32_bf16(ahi0, bhi[0], acc, 0, 0, 0);
        acc = __builtin_amdgcn_mfma_f32_16x16x32_bf16(alo0, bhi[0], acc, 0, 0, 0);
        acc = __builtin_amdgcn_mfma_f32_16x16x32_bf16(ahi0, blo[0], acc, 0, 0, 0);
        acc = __builtin_amdgcn_mfma_f32_16x16x32_bf16(ahi1, bhi[1], acc, 0, 0, 0);
        acc = __builtin_amdgcn_mfma_f32_16x16x32_bf16(alo1, bhi[1], acc, 0, 0, 0);
        acc = __builtin_amdgcn_mfma_f32_16x16x32_bf16(ahi1, blo[1], acc, 0, 0, 0);
        acc = __builtin_amdgcn_mfma_f32_16x16x32_bf16(ahi2, bhi[2], acc, 0, 0, 0);
        acc = __builtin_amdgcn_mfma_f32_16x16x32_bf16(alo2, bhi[2], acc, 0, 0, 0);
        acc = __builtin_amdgcn_mfma_f32_16x16x32_bf16(ahi2, blo[2], acc, 0, 0, 0);

        // epilogue: bias + tanh, split hi/lo, write h(t) into buf pn
        // C/D layout: col = lane&15 -> j, row = q*4 + r -> local batch
        #pragma unroll
        for (int r = 0; r < 4; r++) {
            float h = fast_tanh(acc[r] + bias);
            hreg[r] = h;
            int brow = q * 4 + r;
            short hi = f2bf(h);
            Ahi[pn][brow][j] = hi;
            Alo[pn][brow][j] = f2bf(h - bf2f(hi));
        }
        __syncthreads();
    }

    // final head: out[b] = sum_j h[b][j] * fc_w[j] + fc_b
    #pragma unroll
    for (int r = 0; r < 4; r++) hfin[q * 4 + r][j] = hreg[r];
    __syncthreads();
    if (tid < BPB) {
        float s = fc_b[0];
        for (int k = 0; k < 64; k++) s += hfin[tid][k] * fc_w[k];
        out[b0 + tid] = s;
    }
}

extern "C" void kernel_launch(void* const* d_in, const int* in_sizes, int n_in,
                              void* d_out, int out_size, void* d_ws, size_t ws_size,
                              hipStream_t stream) {
    const float* x    = (const float*)d_in[0];
    const float* W_ih = (const float*)d_in[1];
    const float* W_hh = (const float*)d_in[2];
    const float* b_ih = (const float*)d_in[3];
    const float* b_hh = (const float*)d_in[4];
    const float* fc_w = (const float*)d_in[5];
    const float* fc_b = (const float*)d_in[6];
    float* out = (float*)d_out;

    rnn_fused<<<4096 / BPB, 256, 0, stream>>>(x, W_ih, W_hh, b_ih, b_hh, fc_w, fc_b, out);
}

// Round 2
// 369.583 us; speedup vs baseline: 1.3231x; 1.3231x over previous
//
#include <hip/hip_runtime.h>

// RNN: B=4096, T=512, I=15, H=64, O=1
// Block = 256 threads = 4 waves, owns 16 batch rows for all 512 steps.
// Per step: preact[16b][64j] = A[16][96] * Waug[96][64], A=[h|x_t|pad] in LDS
// (hi + lo-compensation for h), Waug in registers (hi+lo).
// R1: deep x-prefetch (D=8) + raw s_barrier WITHOUT vmcnt drain (global
// prefetch loads stay in flight across the barrier), 3 indep MFMA chains,
// x-lo dropped (5 ds_read_b128/step instead of 6).

#define T_STEPS 512
#define I_DIM 15
#define BPB 16            // batches per block
#define ROWSH 104         // LDS row stride in shorts; mult of 8 (b128 align), 2-way banks
#define DPF 8             // x prefetch depth (divides T_STEPS)

typedef __attribute__((ext_vector_type(8))) short short8;
typedef __attribute__((ext_vector_type(4))) float float4v;

__device__ __forceinline__ short f2bf_rne(float f) {
    union { float f; unsigned u; } v; v.f = f;
    unsigned r = (v.u + 0x7FFFu + ((v.u >> 16) & 1u)) >> 16;   // round-nearest-even
    return (short)r;
}
__device__ __forceinline__ float bf2f(short s) {
    union { float f; unsigned u; } v;
    v.u = ((unsigned)(unsigned short)s) << 16;
    return v.f;
}
__device__ __forceinline__ float fast_tanh(float x) {
    x = fminf(30.f, fmaxf(-30.f, x));
    float e = __builtin_exp2f(x * 2.8853900817779268f);  // e^(2x)
    return (e - 1.f) * __builtin_amdgcn_rcpf(e + 1.f);
}

__global__ __launch_bounds__(256) void rnn_fused(
    const float* __restrict__ x,     // [4096][512][15]
    const float* __restrict__ W_ih,  // [64][15]
    const float* __restrict__ W_hh,  // [64][64]
    const float* __restrict__ b_ih,  // [64]
    const float* __restrict__ b_hh,  // [64]
    const float* __restrict__ fc_w,  // [1][64]
    const float* __restrict__ fc_b,  // [1]
    float* __restrict__ out)         // [4096]
{
    __shared__ __align__(16) short Ahi[2][BPB][ROWSH];
    __shared__ __align__(16) short Alo[2][BPB][ROWSH];
    __shared__ float hfin[BPB][65];

    const int tid  = threadIdx.x;
    const int wave = tid >> 6;
    const int lane = tid & 63;
    const int q    = lane >> 4;     // quad
    const int n    = lane & 15;     // A-row (batch) on read; C/D col (j) on write
    const int j    = wave * 16 + n; // hidden column this lane accumulates
    const int b0   = blockIdx.x * BPB;

    // zero LDS (h0 = 0; pad columns must stay 0 in both buffers)
    for (int idx = tid; idx < 2 * BPB * ROWSH; idx += 256) {
        ((short*)Ahi)[idx] = 0;
        ((short*)Alo)[idx] = 0;
    }

    // --- B fragments (Waug columns for this lane's j), hi+lo, in regs ---
    // value Waug[k][j], k = c*32 + q*8 + e
    short8 bhi[3], blo[3];
    for (int c = 0; c < 3; c++) {
        for (int e = 0; e < 8; e++) {
            int k = c * 32 + q * 8 + e;
            float w = 0.f;
            if (k < 64)       w = W_hh[j * 64 + k];
            else if (k < 79)  w = W_ih[j * 15 + (k - 64)];
            short hi = f2bf_rne(w);
            float rem = w - bf2f(hi);   // exact residual of hi
            bhi[c][e] = hi;
            blo[c][e] = f2bf_rne(rem);
        }
    }
    const float bias = b_ih[j] + b_hh[j];

    // x staging role: thread tid<240 handles x[b0+xb][*][xi]
    const int xb = tid / I_DIM, xi = tid - xb * I_DIM;
    const bool xactive = tid < BPB * I_DIM;
    const float* xrow = x + (size_t)(b0 + xb) * T_STEPS * I_DIM + xi;

    __syncthreads();   // zero-init visible before x(0) staging (fixes R0 race)

    float xv[DPF];
    if (xactive) {
        // x(0) directly into buf 0
        float v0 = xrow[0];
        Ahi[0][xb][64 + xi] = f2bf_rne(v0);
        // preload pipeline: slot d%DPF holds x(d), d=1..DPF
        #pragma unroll
        for (int d = 1; d <= DPF; d++)
            xv[d & (DPF - 1)] = xrow[(size_t)d * I_DIM];
    }
    // raw barrier: LDS drained, global prefetch loads stay in flight
    asm volatile("s_waitcnt lgkmcnt(0)\n\ts_barrier" ::: "memory");

    float hreg[4] = {0.f, 0.f, 0.f, 0.f};

    for (int tb = 0; tb < T_STEPS / DPF; tb++) {
        #pragma unroll
        for (int u = 0; u < DPF; u++) {
            const int t  = tb * DPF + u;
            const int p  = u & 1, pn = p ^ 1;

            // A fragments: row m = n (batch), k = c*32 + q*8 + e
            const short* rowh = &Ahi[p][n][0];
            const short* rowl = &Alo[p][n][0];
            short8 ahi0 = *(const short8*)(rowh + 0 * 32 + q * 8);
            short8 ahi1 = *(const short8*)(rowh + 1 * 32 + q * 8);
            short8 ahi2 = *(const short8*)(rowh + 2 * 32 + q * 8);
            short8 alo0 = *(const short8*)(rowl + 0 * 32 + q * 8);
            short8 alo1 = *(const short8*)(rowl + 1 * 32 + q * 8);

            // stage x(t+1) into other buffer from the pipeline; refill slot
            if (xactive) {
                float v = xv[(u + 1) & (DPF - 1)];
                Ahi[pn][xb][64 + xi] = f2bf_rne(v);
                int tload = t + 1 + DPF;
                if (tload > T_STEPS - 1) tload = T_STEPS - 1;  // clamped dummy
                xv[(u + 1) & (DPF - 1)] = xrow[(size_t)tload * I_DIM];
            }

            // 3 independent accumulator chains (3 + 2 + 3 MFMAs)
            float4v acc0 = {0.f, 0.f, 0.f, 0.f};
            float4v acc1 = {0.f, 0.f, 0.f, 0.f};
            float4v acc2 = {0.f, 0.f, 0.f, 0.f};
            acc0 = __builtin_amdgcn_mfma_f32_16x16x32_bf16(ahi0, bhi[0], acc0, 0, 0, 0);
            acc1 = __builtin_amdgcn_mfma_f32_16x16x32_bf16(alo0, bhi[0], acc1, 0, 0, 0);
            acc2 = __builtin_amdgcn_mfma_f32_16x16x32_bf16(ahi0, blo[0], acc2, 0, 0, 0);
            acc0 = __builtin_amdgcn_mfma_f32_16x16x32_bf16(ahi1, bhi[1], acc0, 0, 0, 0);
            acc1 = __builtin_amdgcn_mfma_f32_16x16x32_bf16(alo1, bhi[1], acc1, 0, 0, 0);
            acc2 = __builtin_amdgcn_mfma_f32_16x16x32_bf16(ahi1, blo[1], acc2, 0, 0, 0);
            acc0 = __builtin_amdgcn_mfma_f32_16x16x32_bf16(ahi2, bhi[2], acc0, 0, 0, 0);
            acc2 = __builtin_amdgcn_mfma_f32_16x16x32_bf16(ahi2, blo[2], acc2, 0, 0, 0);

            // epilogue: bias + tanh, truncation split (lo compensates hi exactly)
            // C/D layout: col = lane&15 -> j, row = q*4 + r -> local batch
            #pragma unroll
            for (int r = 0; r < 4; r++) {
                float pre = (acc0[r] + acc1[r]) + (acc2[r] + bias);
                float h = fast_tanh(pre);
                hreg[r] = h;
                const int brow = q * 4 + r;
                union { float f; unsigned uu; } hv; hv.f = h;
                short hi = (short)(hv.uu >> 16);           // truncate
                union { float f; unsigned uu; } hb; hb.uu = hv.uu & 0xFFFF0000u;
                float rem = h - hb.f;                       // exact residual
                union { float f; unsigned uu; } rv; rv.f = rem;
                short lo = (short)(rv.uu >> 16);            // truncate (2^-16 rel)
                Ahi[pn][brow][j] = hi;
                Alo[pn][brow][j] = lo;
            }
            // raw barrier: only LDS drained; x prefetch stays outstanding
            asm volatile("s_waitcnt lgkmcnt(0)\n\ts_barrier" ::: "memory");
        }
    }

    // final head: out[b] = sum_j h[b][j] * fc_w[j] + fc_b
    #pragma unroll
    for (int r = 0; r < 4; r++) hfin[q * 4 + r][j] = hreg[r];
    __syncthreads();
    if (tid < BPB) {
        float s = fc_b[0];
        for (int k = 0; k < 64; k++) s += hfin[tid][k] * fc_w[k];
        out[b0 + tid] = s;
    }
}

extern "C" void kernel_launch(void* const* d_in, const int* in_sizes, int n_in,
                              void* d_out, int out_size, void* d_ws, size_t ws_size,
                              hipStream_t stream) {
    const float* x    = (const float*)d_in[0];
    const float* W_ih = (const float*)d_in[1];
    const float* W_hh = (const float*)d_in[2];
    const float* b_ih = (const float*)d_in[3];
    const float* b_hh = (const float*)d_in[4];
    const float* fc_w = (const float*)d_in[5];
    const float* fc_b = (const float*)d_in[6];
    float* out = (float*)d_out;

    rnn_fused<<<4096 / BPB, 256, 0, stream>>>(x, W_ih, W_hh, b_ih, b_hh, fc_w, fc_b, out);
}